// Round 5
// baseline (305.578 us; speedup 1.0000x reference)
//
#include <hip/hip_runtime.h>
#include <hip/hip_bf16.h>

// ---------------- common ----------------
typedef __attribute__((ext_vector_type(8))) short bf16x8;
typedef __attribute__((ext_vector_type(16))) float f32x16;
typedef __attribute__((ext_vector_type(4))) unsigned short u16x4;

#define M_DIM 8192
#define N_DIM 4096
#define K_DIM 4096
#define BM 256
#define BN 256
#define BK 64
#define NT2 (K_DIM / BK)  // 64

static __device__ inline unsigned short f32_to_bf16(float f) {
  unsigned int u = __float_as_uint(f);
  unsigned int r = u + 0x7FFFu + ((u >> 16) & 1u);  // RNE; inputs are finite
  return (unsigned short)(r >> 16);
}
static __device__ inline float bf16_to_f32(unsigned short h) {
  return __uint_as_float(((unsigned int)h) << 16);
}

static __device__ inline void gload_lds16(const void* g, void* l) {
  __builtin_amdgcn_global_load_lds(
      (const __attribute__((address_space(1))) unsigned int*)g,
      (__attribute__((address_space(3))) unsigned int*)l,
      16, 0, 0);
}

// ---------------- prep: x fp32 -> bf16, plus row sums ----------------
__global__ __launch_bounds__(256) void prep_x_kernel(
    const float* __restrict__ x, unsigned short* __restrict__ xb,
    float* __restrict__ sx) {
  const int row = blockIdx.x;
  const int tid = threadIdx.x;
  const float4* xr = (const float4*)(x + (long)row * K_DIM);
  u16x4* xo = (u16x4*)(xb + (long)row * K_DIM);
  float sum = 0.f;
#pragma unroll
  for (int i = 0; i < 4; ++i) {
    float4 v = xr[i * 256 + tid];
    float vv[4] = {v.x, v.y, v.z, v.w};
    u16x4 h;
#pragma unroll
    for (int j = 0; j < 4; ++j) {
      unsigned short b = f32_to_bf16(vv[j]);
      h[j] = b;
      sum += bf16_to_f32(b);  // sum of rounded values for consistency
    }
    xo[i * 256 + tid] = h;
  }
#pragma unroll
  for (int off = 32; off > 0; off >>= 1) sum += __shfl_down(sum, off, 64);
  __shared__ float red[4];
  const int lane = tid & 63, wv = tid >> 6;
  if (lane == 0) red[wv] = sum;
  __syncthreads();
  if (tid == 0) sx[row] = red[0] + red[1] + red[2] + red[3];
}

// ---------------- prep: qweight int32 -> bf16 (exact, values 0..255) ----------------
__global__ __launch_bounds__(256) void prep_q_kernel(
    const int* __restrict__ q, unsigned short* __restrict__ qb, long n4) {
  long idx = (long)blockIdx.x * blockDim.x + threadIdx.x;
  const long stride = (long)gridDim.x * blockDim.x;
  const int4* qi = (const int4*)q;
  u16x4* qo = (u16x4*)qb;
  for (long i = idx; i < n4; i += stride) {
    int4 v = qi[i];
    u16x4 h;
    h[0] = f32_to_bf16((float)v.x);
    h[1] = f32_to_bf16((float)v.y);
    h[2] = f32_to_bf16((float)v.z);
    h[3] = f32_to_bf16((float)v.w);
    qo[i] = h;
  }
}

// ---------------- GEMM: 256x256, BK=64, 32x32x16 MFMA, 4-phase, counted vmcnt, XCD swizzle ----
// 8 waves (2Mx4N); wave tile 128x64 = 4 m-frags x 2 n-frags (32x32). Per K-tile:
// 32 MFMA, 24 ds_read_b128 (8/8/4/4 per phase). acc = 8 x f32x16 = 128 AGPR.
// Ledger (same as R4, re-verified): stage order per tile t+1: P0:{A0,A2} P1:{B0,B2}
// P2:{B1,B3} P3:{A1,A3}. vmcnt(4) before P2 forces old A{1,3} (P2/P3 read A sweeps 1,3);
// vmcnt(2) at tile boundary forces all-B + A{0,2} of t+1 (P0/P1 read A sweeps 0|2 + B sweep wc).
__global__ __launch_bounds__(512, 2) void wq_gemm_kernel(
    const unsigned short* __restrict__ A,   // xb [M][K] bf16
    const unsigned short* __restrict__ B,   // qb [N][K] bf16
    const float* __restrict__ sx,           // [M]
    const float* __restrict__ scales,       // [N]
    const float* __restrict__ zps,          // [N]
    const float* __restrict__ bias,         // [N]
    float* __restrict__ C) {                // [M][N]
  __shared__ __align__(16) char lds[2 * 65536];  // [buf][A:32KB | B:32KB]

  const int tid = threadIdx.x;
  const int lane = tid & 63;
  const int wv = tid >> 6;
  const int wr = wv >> 2, wc = wv & 3;  // 2x4 waves; wave tile 128 rows x 64 cols

  // T1: XCD-aware chunked swizzle (nwg=512, 512%8==0 -> simple bijective form).
  const int wg = blockIdx.x;
  const int lid = (wg & 7) * 64 + (wg >> 3);
  const int bx = lid & 15, by = lid >> 4;
  const int brow = by * BM;
  const int bcol = bx * BN;

  f32x16 acc[4][2] = {};

  // ---- staging (512 threads; sweep = 8KB = 64 rows x 128B = 8 chunks of 16B) ----
  // LDS dest linear; src chunk pre-swizzled: c_src = c ^ (row&7)  (3-bit involution).
  const int srow = tid >> 3;                                // 0..63 within sweep
  const int schunk = ((tid & 7) ^ (srow & 7)) * 16;
  const int wub = (tid & ~63) * 16;                         // wave-uniform LDS base
  const char* gAs = (const char*)A + ((long)(brow + srow) * K_DIM) * 2 + schunk;
  const char* gBs = (const char*)B + ((long)(bcol + srow) * K_DIM) * 2 + schunk;
  char* ldsA0p = lds;
  char* ldsB0p = lds + 32768;
  char* ldsA1p = lds + 65536;
  char* ldsB1p = lds + 65536 + 32768;

#define STAGE(GBASE, LBASE, J, T1)                                      \
  gload_lds16((GBASE) + (long)(J) * 524288 + (long)(T1) * 128,          \
              (LBASE) + (J) * 8192 + wub)

  // ---- fragment read offsets ----
  // 32x32x16 bf16 operand: lane holds [row=lane&31][k = (lane>>5)*8 + 0..7].
  // Read chunk(ks) = (ks*2 + kg) ^ (row5&7); fm/fn add 32*128 = 4096B immediates.
  const int row5 = lane & 31;
  const int kg = lane >> 5;
  int aoff[4], boff[4];
#pragma unroll
  for (int ks = 0; ks < 4; ++ks) {
    const int ch = ((ks * 2 + kg) ^ (row5 & 7)) * 16;
    aoff[ks] = (wr * 128 + row5) * 128 + ch;
    boff[ks] = (wc * 64 + row5) * 128 + ch;
  }

#define RD_A(BUF, FM, KS) (*(const bf16x8*)((BUF) + aoff[KS] + (FM) * 4096))
#define RD_B(BUF, FN, KS) (*(const bf16x8*)((BUF) + 32768 + boff[KS] + (FN) * 4096))
#define MMA(FM, FN, AV, BV)                                                   \
  acc[FM][FN] = __builtin_amdgcn_mfma_f32_32x32x16_bf16(AV, BV, acc[FM][FN], 0, 0, 0)

#define BAR() asm volatile("s_barrier" ::: "memory")
#define VMC(N) asm volatile("s_waitcnt vmcnt(" #N ")" ::: "memory")

  // ---- prologue: full stage of tile 0 into buf0 ----
  STAGE(gAs, ldsA0p, 0, 0); STAGE(gAs, ldsA0p, 2, 0);
  STAGE(gBs, ldsB0p, 0, 0); STAGE(gBs, ldsB0p, 2, 0);
  STAGE(gBs, ldsB0p, 1, 0); STAGE(gBs, ldsB0p, 3, 0);
  STAGE(gAs, ldsA0p, 1, 0); STAGE(gAs, ldsA0p, 3, 0);
  VMC(0);
  BAR();

  bf16x8 a0, a1, a2, a3, b00, b10, b01, b11, b02, b12, b03, b13;

  // ---- main loop: tiles 0..NT2-2, staging t+1 into other buf ----
  for (int t = 0; t < NT2 - 1; ++t) {
    const int cb = t & 1;
    const char* bufc = lds + cb * 65536;       // current buffer base
    char* dA = cb ? ldsA0p : ldsA1p;
    char* dB = cb ? ldsB0p : ldsB1p;
    const int t1 = t + 1;
    // P0: row-half {0,1} x ks {0,1}
    a0 = RD_A(bufc, 0, 0); a1 = RD_A(bufc, 1, 0);
    a2 = RD_A(bufc, 0, 1); a3 = RD_A(bufc, 1, 1);
    b00 = RD_B(bufc, 0, 0); b10 = RD_B(bufc, 1, 0);
    b01 = RD_B(bufc, 0, 1); b11 = RD_B(bufc, 1, 1);
    STAGE(gAs, dA, 0, t1); STAGE(gAs, dA, 2, t1);
    BAR();
    __builtin_amdgcn_s_setprio(1);
    MMA(0, 0, a0, b00); MMA(0, 1, a0, b10);
    MMA(1, 0, a1, b00); MMA(1, 1, a1, b10);
    MMA(0, 0, a2, b01); MMA(0, 1, a2, b11);
    MMA(1, 0, a3, b01); MMA(1, 1, a3, b11);
    __builtin_amdgcn_s_setprio(0);
    BAR();
    // P1: row-half {0,1} x ks {2,3}
    a0 = RD_A(bufc, 0, 2); a1 = RD_A(bufc, 1, 2);
    a2 = RD_A(bufc, 0, 3); a3 = RD_A(bufc, 1, 3);
    b02 = RD_B(bufc, 0, 2); b12 = RD_B(bufc, 1, 2);
    b03 = RD_B(bufc, 0, 3); b13 = RD_B(bufc, 1, 3);
    STAGE(gBs, dB, 0, t1); STAGE(gBs, dB, 2, t1);
    BAR();
    __builtin_amdgcn_s_setprio(1);
    MMA(0, 0, a0, b02); MMA(0, 1, a0, b12);
    MMA(1, 0, a1, b02); MMA(1, 1, a1, b12);
    MMA(0, 0, a2, b03); MMA(0, 1, a2, b13);
    MMA(1, 0, a3, b03); MMA(1, 1, a3, b13);
    __builtin_amdgcn_s_setprio(0);
    VMC(4);  // old {A1,A3} landed -> P2/P3 A-sweep-{1,3} reads safe
    BAR();
    // P2: row-half {2,3} x ks {0,1}
    a0 = RD_A(bufc, 2, 0); a1 = RD_A(bufc, 3, 0);
    a2 = RD_A(bufc, 2, 1); a3 = RD_A(bufc, 3, 1);
    STAGE(gBs, dB, 1, t1); STAGE(gBs, dB, 3, t1);
    BAR();
    __builtin_amdgcn_s_setprio(1);
    MMA(2, 0, a0, b00); MMA(2, 1, a0, b10);
    MMA(3, 0, a1, b00); MMA(3, 1, a1, b10);
    MMA(2, 0, a2, b01); MMA(2, 1, a2, b11);
    MMA(3, 0, a3, b01); MMA(3, 1, a3, b11);
    __builtin_amdgcn_s_setprio(0);
    BAR();
    // P3: row-half {2,3} x ks {2,3}
    a0 = RD_A(bufc, 2, 2); a1 = RD_A(bufc, 3, 2);
    a2 = RD_A(bufc, 2, 3); a3 = RD_A(bufc, 3, 3);
    STAGE(gAs, dA, 1, t1); STAGE(gAs, dA, 3, t1);
    BAR();
    __builtin_amdgcn_s_setprio(1);
    MMA(2, 0, a0, b02); MMA(2, 1, a0, b12);
    MMA(3, 0, a1, b02); MMA(3, 1, a1, b12);
    MMA(2, 0, a2, b03); MMA(2, 1, a2, b13);
    MMA(3, 0, a3, b03); MMA(3, 1, a3, b13);
    __builtin_amdgcn_s_setprio(0);
    VMC(2);  // tile t+1: all B + A{0,2} landed -> next P0/P1 safe
    BAR();
  }

  // ---- tail: tile NT2-1 (buf1), no staging ----
  {
    const char* bufc = lds + 65536;
    a0 = RD_A(bufc, 0, 0); a1 = RD_A(bufc, 1, 0);
    a2 = RD_A(bufc, 0, 1); a3 = RD_A(bufc, 1, 1);
    b00 = RD_B(bufc, 0, 0); b10 = RD_B(bufc, 1, 0);
    b01 = RD_B(bufc, 0, 1); b11 = RD_B(bufc, 1, 1);
    MMA(0, 0, a0, b00); MMA(0, 1, a0, b10);
    MMA(1, 0, a1, b00); MMA(1, 1, a1, b10);
    MMA(0, 0, a2, b01); MMA(0, 1, a2, b11);
    MMA(1, 0, a3, b01); MMA(1, 1, a3, b11);
    a0 = RD_A(bufc, 0, 2); a1 = RD_A(bufc, 1, 2);
    a2 = RD_A(bufc, 0, 3); a3 = RD_A(bufc, 1, 3);
    b02 = RD_B(bufc, 0, 2); b12 = RD_B(bufc, 1, 2);
    b03 = RD_B(bufc, 0, 3); b13 = RD_B(bufc, 1, 3);
    MMA(0, 0, a0, b02); MMA(0, 1, a0, b12);
    MMA(1, 0, a1, b02); MMA(1, 1, a1, b12);
    MMA(0, 0, a2, b03); MMA(0, 1, a2, b13);
    MMA(1, 0, a3, b03); MMA(1, 1, a3, b13);
    VMC(0);  // drain tile's {A1,A3}
    BAR();
    a0 = RD_A(bufc, 2, 0); a1 = RD_A(bufc, 3, 0);
    a2 = RD_A(bufc, 2, 1); a3 = RD_A(bufc, 3, 1);
    MMA(2, 0, a0, b00); MMA(2, 1, a0, b10);
    MMA(3, 0, a1, b00); MMA(3, 1, a1, b10);
    MMA(2, 0, a2, b01); MMA(2, 1, a2, b11);
    MMA(3, 0, a3, b01); MMA(3, 1, a3, b11);
    a0 = RD_A(bufc, 2, 2); a1 = RD_A(bufc, 3, 2);
    a2 = RD_A(bufc, 2, 3); a3 = RD_A(bufc, 3, 3);
    MMA(2, 0, a0, b02); MMA(2, 1, a0, b12);
    MMA(3, 0, a1, b02); MMA(3, 1, a1, b12);
    MMA(2, 0, a2, b03); MMA(2, 1, a2, b13);
    MMA(3, 0, a3, b03); MMA(3, 1, a3, b13);
  }

  // ---- epilogue: 32x32 C/D layout col=lane&31, row=(r&3)+8*(r>>2)+4*(lane>>5) ----
  float sc[2], zp[2], bs[2];
  int coln[2];
#pragma unroll
  for (int fn = 0; fn < 2; ++fn) {
    coln[fn] = bcol + wc * 64 + fn * 32 + row5;
    sc[fn] = scales[coln[fn]];
    zp[fn] = zps[coln[fn]];
    bs[fn] = bias[coln[fn]];
  }
#pragma unroll
  for (int fm = 0; fm < 4; ++fm) {
#pragma unroll
    for (int r = 0; r < 16; ++r) {
      const int grow = brow + wr * 128 + fm * 32 + (r & 3) + 8 * (r >> 2) + 4 * kg;
      const float sxv = sx[grow];
#pragma unroll
      for (int fn = 0; fn < 2; ++fn) {
        C[(long)grow * N_DIM + coln[fn]] =
            sc[fn] * (acc[fm][fn][r] - zp[fn] * sxv) + bs[fn];
      }
    }
  }
}

// ---------------- launch ----------------
extern "C" void kernel_launch(void* const* d_in, const int* in_sizes, int n_in,
                              void* d_out, int out_size, void* d_ws, size_t ws_size,
                              hipStream_t stream) {
  const float* x = (const float*)d_in[0];
  const int* qw = (const int*)d_in[1];
  const float* scales = (const float*)d_in[2];
  const float* zps = (const float*)d_in[3];
  const float* bias = (const float*)d_in[4];
  float* out = (float*)d_out;

  char* ws = (char*)d_ws;
  unsigned short* xb = (unsigned short*)ws;                              // 64 MB
  unsigned short* qb = (unsigned short*)(ws + (size_t)64 * 1024 * 1024); // 32 MB
  float* sx = (float*)(ws + (size_t)96 * 1024 * 1024);                   // 32 KB

  hipLaunchKernelGGL(prep_x_kernel, dim3(M_DIM), dim3(256), 0, stream, x, xb, sx);
  hipLaunchKernelGGL(prep_q_kernel, dim3(2048), dim3(256), 0, stream, qw, qb,
                     (long)((long)N_DIM * K_DIM / 4));
  hipLaunchKernelGGL(wq_gemm_kernel, dim3((M_DIM / BM) * (N_DIM / BN)), dim3(512), 0,
                     stream, xb, qb, sx, scales, zps, bias, out);
}

// Round 6
// 304.324 us; speedup vs baseline: 1.0041x; 1.0041x over previous
//
#include <hip/hip_runtime.h>
#include <hip/hip_bf16.h>

// ---------------- common ----------------
typedef __attribute__((ext_vector_type(8))) short bf16x8;
typedef __attribute__((ext_vector_type(16))) float f32x16;
typedef __attribute__((ext_vector_type(4))) unsigned short u16x4;

#define M_DIM 8192
#define N_DIM 4096
#define K_DIM 4096
#define BM 256
#define BN 256
#define BK 64
#define NT2 (K_DIM / BK)  // 64

static __device__ inline unsigned short f32_to_bf16(float f) {
  unsigned int u = __float_as_uint(f);
  unsigned int r = u + 0x7FFFu + ((u >> 16) & 1u);  // RNE; inputs are finite
  return (unsigned short)(r >> 16);
}
static __device__ inline float bf16_to_f32(unsigned short h) {
  return __uint_as_float(((unsigned int)h) << 16);
}

static __device__ inline void gload_lds16(const void* g, void* l) {
  __builtin_amdgcn_global_load_lds(
      (const __attribute__((address_space(1))) unsigned int*)g,
      (__attribute__((address_space(3))) unsigned int*)l,
      16, 0, 0);
}

// ---------------- prep: x fp32 -> bf16, plus row sums ----------------
__global__ __launch_bounds__(256) void prep_x_kernel(
    const float* __restrict__ x, unsigned short* __restrict__ xb,
    float* __restrict__ sx) {
  const int row = blockIdx.x;
  const int tid = threadIdx.x;
  const float4* xr = (const float4*)(x + (long)row * K_DIM);
  u16x4* xo = (u16x4*)(xb + (long)row * K_DIM);
  float sum = 0.f;
#pragma unroll
  for (int i = 0; i < 4; ++i) {
    float4 v = xr[i * 256 + tid];
    float vv[4] = {v.x, v.y, v.z, v.w};
    u16x4 h;
#pragma unroll
    for (int j = 0; j < 4; ++j) {
      unsigned short b = f32_to_bf16(vv[j]);
      h[j] = b;
      sum += bf16_to_f32(b);  // sum of rounded values for consistency
    }
    xo[i * 256 + tid] = h;
  }
#pragma unroll
  for (int off = 32; off > 0; off >>= 1) sum += __shfl_down(sum, off, 64);
  __shared__ float red[4];
  const int lane = tid & 63, wv = tid >> 6;
  if (lane == 0) red[wv] = sum;
  __syncthreads();
  if (tid == 0) sx[row] = red[0] + red[1] + red[2] + red[3];
}

// ---------------- prep: qweight int32 -> bf16 (exact, values 0..255) ----------------
__global__ __launch_bounds__(256) void prep_q_kernel(
    const int* __restrict__ q, unsigned short* __restrict__ qb, long n4) {
  long idx = (long)blockIdx.x * blockDim.x + threadIdx.x;
  const long stride = (long)gridDim.x * blockDim.x;
  const int4* qi = (const int4*)q;
  u16x4* qo = (u16x4*)qb;
  for (long i = idx; i < n4; i += stride) {
    int4 v = qi[i];
    u16x4 h;
    h[0] = f32_to_bf16((float)v.x);
    h[1] = f32_to_bf16((float)v.y);
    h[2] = f32_to_bf16((float)v.z);
    h[3] = f32_to_bf16((float)v.w);
    qo[i] = h;
  }
}

// ---------------- GEMM: 256x256, BK=64, 32x32x16 MFMA, 4-phase, counted vmcnt, XCD swizzle ----
// IDENTICAL to R5 except synchronization primitives:
//   BAR: __builtin_amdgcn_s_barrier()  (no "memory" clobber -> no compiler-inserted
//        s_waitcnt vmcnt(0) lgkmcnt(0) drain before it)
//   VMC: clobber-free asm s_waitcnt vmcnt(N) + sched_barrier(0) (rule #18 fence so
//        ds_reads of just-landed buffers can't hoist above the wait)
// Ledger (verified): stage order per tile t+1: P0:{A0,A2} P1:{B0,B2} P2:{B1,B3} P3:{A1,A3}.
//   P0/P1 read A sweeps {0|2} (wr-dependent) + B sweep wc; P2/P3 read A sweeps {1|3}.
//   VMC(4) before P2 forces old {A1,A3}; VMC(2) at boundary forces t+1's all-B + {A0,A2}.
__global__ __launch_bounds__(512, 2) void wq_gemm_kernel(
    const unsigned short* __restrict__ A,   // xb [M][K] bf16
    const unsigned short* __restrict__ B,   // qb [N][K] bf16
    const float* __restrict__ sx,           // [M]
    const float* __restrict__ scales,       // [N]
    const float* __restrict__ zps,          // [N]
    const float* __restrict__ bias,         // [N]
    float* __restrict__ C) {                // [M][N]
  __shared__ __align__(16) char lds[2 * 65536];  // [buf][A:32KB | B:32KB]

  const int tid = threadIdx.x;
  const int lane = tid & 63;
  const int wv = tid >> 6;
  const int wr = wv >> 2, wc = wv & 3;  // 2x4 waves; wave tile 128 rows x 64 cols

  // T1: XCD-aware chunked swizzle (nwg=512, 512%8==0 -> simple bijective form).
  const int wg = blockIdx.x;
  const int lid = (wg & 7) * 64 + (wg >> 3);
  const int bx = lid & 15, by = lid >> 4;
  const int brow = by * BM;
  const int bcol = bx * BN;

  f32x16 acc[4][2] = {};

  // ---- staging (512 threads; sweep = 8KB = 64 rows x 128B = 8 chunks of 16B) ----
  // LDS dest linear; src chunk pre-swizzled: c_src = c ^ (row&7)  (3-bit involution).
  const int srow = tid >> 3;                                // 0..63 within sweep
  const int schunk = ((tid & 7) ^ (srow & 7)) * 16;
  const int wub = (tid & ~63) * 16;                         // wave-uniform LDS base
  const char* gAs = (const char*)A + ((long)(brow + srow) * K_DIM) * 2 + schunk;
  const char* gBs = (const char*)B + ((long)(bcol + srow) * K_DIM) * 2 + schunk;
  char* ldsA0p = lds;
  char* ldsB0p = lds + 32768;
  char* ldsA1p = lds + 65536;
  char* ldsB1p = lds + 65536 + 32768;

#define STAGE(GBASE, LBASE, J, T1)                                      \
  gload_lds16((GBASE) + (long)(J) * 524288 + (long)(T1) * 128,          \
              (LBASE) + (J) * 8192 + wub)

  // ---- fragment read offsets ----
  // 32x32x16 bf16 operand: lane holds [row=lane&31][k = (lane>>5)*8 + 0..7].
  // Read chunk(ks) = (ks*2 + kg) ^ (row5&7); fm/fn add 32*128 = 4096B immediates.
  const int row5 = lane & 31;
  const int kg = lane >> 5;
  int aoff[4], boff[4];
#pragma unroll
  for (int ks = 0; ks < 4; ++ks) {
    const int ch = ((ks * 2 + kg) ^ (row5 & 7)) * 16;
    aoff[ks] = (wr * 128 + row5) * 128 + ch;
    boff[ks] = (wc * 64 + row5) * 128 + ch;
  }

#define RD_A(BUF, FM, KS) (*(const bf16x8*)((BUF) + aoff[KS] + (FM) * 4096))
#define RD_B(BUF, FN, KS) (*(const bf16x8*)((BUF) + 32768 + boff[KS] + (FN) * 4096))
#define MMA(FM, FN, AV, BV)                                                   \
  acc[FM][FN] = __builtin_amdgcn_mfma_f32_32x32x16_bf16(AV, BV, acc[FM][FN], 0, 0, 0)

#define BAR() __builtin_amdgcn_s_barrier()
#define VMC(N)                                                                \
  do {                                                                        \
    asm volatile("s_waitcnt vmcnt(" #N ")");                                  \
    __builtin_amdgcn_sched_barrier(0);                                        \
  } while (0)

  // ---- prologue: full stage of tile 0 into buf0 ----
  STAGE(gAs, ldsA0p, 0, 0); STAGE(gAs, ldsA0p, 2, 0);
  STAGE(gBs, ldsB0p, 0, 0); STAGE(gBs, ldsB0p, 2, 0);
  STAGE(gBs, ldsB0p, 1, 0); STAGE(gBs, ldsB0p, 3, 0);
  STAGE(gAs, ldsA0p, 1, 0); STAGE(gAs, ldsA0p, 3, 0);
  VMC(0);
  BAR();

  bf16x8 a0, a1, a2, a3, b00, b10, b01, b11, b02, b12, b03, b13;

  // ---- main loop: tiles 0..NT2-2, staging t+1 into other buf ----
  for (int t = 0; t < NT2 - 1; ++t) {
    const int cb = t & 1;
    const char* bufc = lds + cb * 65536;       // current buffer base
    char* dA = cb ? ldsA0p : ldsA1p;
    char* dB = cb ? ldsB0p : ldsB1p;
    const int t1 = t + 1;
    // P0: row-half {0,1} x ks {0,1}
    a0 = RD_A(bufc, 0, 0); a1 = RD_A(bufc, 1, 0);
    a2 = RD_A(bufc, 0, 1); a3 = RD_A(bufc, 1, 1);
    b00 = RD_B(bufc, 0, 0); b10 = RD_B(bufc, 1, 0);
    b01 = RD_B(bufc, 0, 1); b11 = RD_B(bufc, 1, 1);
    STAGE(gAs, dA, 0, t1); STAGE(gAs, dA, 2, t1);
    BAR();
    __builtin_amdgcn_s_setprio(1);
    MMA(0, 0, a0, b00); MMA(0, 1, a0, b10);
    MMA(1, 0, a1, b00); MMA(1, 1, a1, b10);
    MMA(0, 0, a2, b01); MMA(0, 1, a2, b11);
    MMA(1, 0, a3, b01); MMA(1, 1, a3, b11);
    __builtin_amdgcn_s_setprio(0);
    BAR();
    // P1: row-half {0,1} x ks {2,3}
    a0 = RD_A(bufc, 0, 2); a1 = RD_A(bufc, 1, 2);
    a2 = RD_A(bufc, 0, 3); a3 = RD_A(bufc, 1, 3);
    b02 = RD_B(bufc, 0, 2); b12 = RD_B(bufc, 1, 2);
    b03 = RD_B(bufc, 0, 3); b13 = RD_B(bufc, 1, 3);
    STAGE(gBs, dB, 0, t1); STAGE(gBs, dB, 2, t1);
    BAR();
    __builtin_amdgcn_s_setprio(1);
    MMA(0, 0, a0, b02); MMA(0, 1, a0, b12);
    MMA(1, 0, a1, b02); MMA(1, 1, a1, b12);
    MMA(0, 0, a2, b03); MMA(0, 1, a2, b13);
    MMA(1, 0, a3, b03); MMA(1, 1, a3, b13);
    __builtin_amdgcn_s_setprio(0);
    VMC(4);  // old {A1,A3} landed -> P2/P3 A-sweep-{1,3} reads safe
    BAR();
    // P2: row-half {2,3} x ks {0,1}
    a0 = RD_A(bufc, 2, 0); a1 = RD_A(bufc, 3, 0);
    a2 = RD_A(bufc, 2, 1); a3 = RD_A(bufc, 3, 1);
    STAGE(gBs, dB, 1, t1); STAGE(gBs, dB, 3, t1);
    BAR();
    __builtin_amdgcn_s_setprio(1);
    MMA(2, 0, a0, b00); MMA(2, 1, a0, b10);
    MMA(3, 0, a1, b00); MMA(3, 1, a1, b10);
    MMA(2, 0, a2, b01); MMA(2, 1, a2, b11);
    MMA(3, 0, a3, b01); MMA(3, 1, a3, b11);
    __builtin_amdgcn_s_setprio(0);
    BAR();
    // P3: row-half {2,3} x ks {2,3}
    a0 = RD_A(bufc, 2, 2); a1 = RD_A(bufc, 3, 2);
    a2 = RD_A(bufc, 2, 3); a3 = RD_A(bufc, 3, 3);
    STAGE(gAs, dA, 1, t1); STAGE(gAs, dA, 3, t1);
    BAR();
    __builtin_amdgcn_s_setprio(1);
    MMA(2, 0, a0, b02); MMA(2, 1, a0, b12);
    MMA(3, 0, a1, b02); MMA(3, 1, a1, b12);
    MMA(2, 0, a2, b03); MMA(2, 1, a2, b13);
    MMA(3, 0, a3, b03); MMA(3, 1, a3, b13);
    __builtin_amdgcn_s_setprio(0);
    VMC(2);  // tile t+1: all B + A{0,2} landed -> next P0/P1 safe
    BAR();
  }

  // ---- tail: tile NT2-1 (buf1), no staging ----
  {
    const char* bufc = lds + 65536;
    a0 = RD_A(bufc, 0, 0); a1 = RD_A(bufc, 1, 0);
    a2 = RD_A(bufc, 0, 1); a3 = RD_A(bufc, 1, 1);
    b00 = RD_B(bufc, 0, 0); b10 = RD_B(bufc, 1, 0);
    b01 = RD_B(bufc, 0, 1); b11 = RD_B(bufc, 1, 1);
    MMA(0, 0, a0, b00); MMA(0, 1, a0, b10);
    MMA(1, 0, a1, b00); MMA(1, 1, a1, b10);
    MMA(0, 0, a2, b01); MMA(0, 1, a2, b11);
    MMA(1, 0, a3, b01); MMA(1, 1, a3, b11);
    a0 = RD_A(bufc, 0, 2); a1 = RD_A(bufc, 1, 2);
    a2 = RD_A(bufc, 0, 3); a3 = RD_A(bufc, 1, 3);
    b02 = RD_B(bufc, 0, 2); b12 = RD_B(bufc, 1, 2);
    b03 = RD_B(bufc, 0, 3); b13 = RD_B(bufc, 1, 3);
    MMA(0, 0, a0, b02); MMA(0, 1, a0, b12);
    MMA(1, 0, a1, b02); MMA(1, 1, a1, b12);
    MMA(0, 0, a2, b03); MMA(0, 1, a2, b13);
    MMA(1, 0, a3, b03); MMA(1, 1, a3, b13);
    VMC(0);  // drain tile's {A1,A3}
    BAR();
    a0 = RD_A(bufc, 2, 0); a1 = RD_A(bufc, 3, 0);
    a2 = RD_A(bufc, 2, 1); a3 = RD_A(bufc, 3, 1);
    MMA(2, 0, a0, b00); MMA(2, 1, a0, b10);
    MMA(3, 0, a1, b00); MMA(3, 1, a1, b10);
    MMA(2, 0, a2, b01); MMA(2, 1, a2, b11);
    MMA(3, 0, a3, b01); MMA(3, 1, a3, b11);
    a0 = RD_A(bufc, 2, 2); a1 = RD_A(bufc, 3, 2);
    a2 = RD_A(bufc, 2, 3); a3 = RD_A(bufc, 3, 3);
    MMA(2, 0, a0, b02); MMA(2, 1, a0, b12);
    MMA(3, 0, a1, b02); MMA(3, 1, a1, b12);
    MMA(2, 0, a2, b03); MMA(2, 1, a2, b13);
    MMA(3, 0, a3, b03); MMA(3, 1, a3, b13);
  }

  // ---- epilogue: 32x32 C/D layout col=lane&31, row=(r&3)+8*(r>>2)+4*(lane>>5) ----
  float sc[2], zp[2], bs[2];
  int coln[2];
#pragma unroll
  for (int fn = 0; fn < 2; ++fn) {
    coln[fn] = bcol + wc * 64 + fn * 32 + row5;
    sc[fn] = scales[coln[fn]];
    zp[fn] = zps[coln[fn]];
    bs[fn] = bias[coln[fn]];
  }
#pragma unroll
  for (int fm = 0; fm < 4; ++fm) {
#pragma unroll
    for (int r = 0; r < 16; ++r) {
      const int grow = brow + wr * 128 + fm * 32 + (r & 3) + 8 * (r >> 2) + 4 * kg;
      const float sxv = sx[grow];
#pragma unroll
      for (int fn = 0; fn < 2; ++fn) {
        C[(long)grow * N_DIM + coln[fn]] =
            sc[fn] * (acc[fm][fn][r] - zp[fn] * sxv) + bs[fn];
      }
    }
  }
}

// ---------------- launch ----------------
extern "C" void kernel_launch(void* const* d_in, const int* in_sizes, int n_in,
                              void* d_out, int out_size, void* d_ws, size_t ws_size,
                              hipStream_t stream) {
  const float* x = (const float*)d_in[0];
  const int* qw = (const int*)d_in[1];
  const float* scales = (const float*)d_in[2];
  const float* zps = (const float*)d_in[3];
  const float* bias = (const float*)d_in[4];
  float* out = (float*)d_out;

  char* ws = (char*)d_ws;
  unsigned short* xb = (unsigned short*)ws;                              // 64 MB
  unsigned short* qb = (unsigned short*)(ws + (size_t)64 * 1024 * 1024); // 32 MB
  float* sx = (float*)(ws + (size_t)96 * 1024 * 1024);                   // 32 KB

  hipLaunchKernelGGL(prep_x_kernel, dim3(M_DIM), dim3(256), 0, stream, x, xb, sx);
  hipLaunchKernelGGL(prep_q_kernel, dim3(2048), dim3(256), 0, stream, qw, qb,
                     (long)((long)N_DIM * K_DIM / 4));
  hipLaunchKernelGGL(wq_gemm_kernel, dim3((M_DIM / BM) * (N_DIM / BN)), dim3(512), 0,
                     stream, xb, qb, sx, scales, zps, bias, out);
}

// Round 7
// 215.628 us; speedup vs baseline: 1.4172x; 1.4113x over previous
//
#include <hip/hip_runtime.h>
#include <hip/hip_bf16.h>

// ---------------- common ----------------
typedef __attribute__((ext_vector_type(4))) int i32x4;
typedef __attribute__((ext_vector_type(16))) int i32x16;

#define M_DIM 8192
#define N_DIM 4096
#define K_DIM 4096
#define BM 256
#define BN 256
#define BK 64
#define NT2 (K_DIM / BK)  // 64

static __device__ inline void gload_lds16(const void* g, void* l) {
  __builtin_amdgcn_global_load_lds(
      (const __attribute__((address_space(1))) unsigned int*)g,
      (__attribute__((address_space(3))) unsigned int*)l,
      16, 0, 0);
}

// ---------------- prep: x fp32 -> i8 (per-row symmetric), row scale + int row-sum ----------------
__global__ __launch_bounds__(256) void prep_x_i8(
    const float* __restrict__ x, char* __restrict__ xq,
    float* __restrict__ rx, float* __restrict__ sxf) {
  const int row = blockIdx.x;
  const int tid = threadIdx.x;
  const float4* xr = (const float4*)(x + (long)row * K_DIM);
  float4 v[4];
  float mx = 0.f;
#pragma unroll
  for (int i = 0; i < 4; ++i) {
    v[i] = xr[i * 256 + tid];
    mx = fmaxf(mx, fmaxf(fmaxf(fabsf(v[i].x), fabsf(v[i].y)),
                         fmaxf(fabsf(v[i].z), fabsf(v[i].w))));
  }
#pragma unroll
  for (int off = 32; off > 0; off >>= 1) mx = fmaxf(mx, __shfl_down(mx, off, 64));
  __shared__ float redm[4];
  __shared__ int reds[4];
  const int lane = tid & 63, w = tid >> 6;
  if (lane == 0) redm[w] = mx;
  __syncthreads();
  const float maxv = fmaxf(fmaxf(redm[0], redm[1]), fmaxf(redm[2], redm[3]));
  const float inv = maxv > 0.f ? 127.f / maxv : 0.f;
  int* xo = (int*)(xq + (long)row * K_DIM);
  int ssum = 0;
#pragma unroll
  for (int i = 0; i < 4; ++i) {
    const int q0 = __float2int_rn(v[i].x * inv);
    const int q1 = __float2int_rn(v[i].y * inv);
    const int q2 = __float2int_rn(v[i].z * inv);
    const int q3 = __float2int_rn(v[i].w * inv);
    ssum += q0 + q1 + q2 + q3;
    xo[i * 256 + tid] =
        (q0 & 255) | ((q1 & 255) << 8) | ((q2 & 255) << 16) | ((q3 & 255) << 24);
  }
#pragma unroll
  for (int off = 32; off > 0; off >>= 1) ssum += __shfl_down(ssum, off, 64);
  if (lane == 0) reds[w] = ssum;
  __syncthreads();
  if (tid == 0) {
    rx[row] = maxv * (1.f / 127.f);
    sxf[row] = (float)(reds[0] + reds[1] + reds[2] + reds[3]);
  }
}

// ---------------- prep: qweight int32 [0,255] -> i8 (q-128), exact ----------------
__global__ __launch_bounds__(256) void prep_q_i8(
    const int* __restrict__ q, char* __restrict__ qb) {
  const long idx = (long)blockIdx.x * blockDim.x + threadIdx.x;  // one int4 -> one int
  const int4 v = ((const int4*)q)[idx];
  const int a = v.x - 128, b = v.y - 128, c = v.z - 128, d = v.w - 128;
  ((int*)qb)[idx] = (a & 255) | ((b & 255) << 8) | ((c & 255) << 16) | ((d & 255) << 24);
}

// ---------------- GEMM: 256x256, BK=64, i8 32x32x32 MFMA, ring-4 LDS, counted vmcnt ----------------
// 8 waves (2Mx4N); wave tile 128x64 = 4 fm x 2 fn (32x32 frags). Per K-tile:
// 16 MFMA + 12 ds_read_b128 per wave; 4 global_load_lds per block (A x2, B x2).
// Ring-4 slots x (A 16KB + B 16KB) = 128 KiB. Depth-2 prefetch; VMC(4) at every
// tile end forces tile t+1 landed while t+2's 4 loads stay in flight (never 0).
// Chunk swizzle (64B rows, 4x16B chunks): c_src = c ^ (row&3) on global source,
// same XOR on read side (LDS dest linear per global_load_lds, rule #21).
__global__ __launch_bounds__(512, 2) void wq_gemm_i8(
    const char* __restrict__ A,             // xq [M][K] i8
    const char* __restrict__ B,             // qb [N][K] i8
    const float* __restrict__ rx,           // [M] row scale
    const float* __restrict__ sxf,          // [M] sum of xi (float, exact)
    const float* __restrict__ scales,       // [N]
    const float* __restrict__ zps,          // [N]
    const float* __restrict__ bias,         // [N]
    float* __restrict__ C) {                // [M][N]
  __shared__ __align__(16) char lds[4 * 32768];

  const int tid = threadIdx.x;
  const int lane = tid & 63;
  const int wv = tid >> 6;
  const int wr = wv >> 2, wc = wv & 3;

  // T1: XCD-aware chunked swizzle (nwg=512, 512%8==0).
  const int wg = blockIdx.x;
  const int lid = (wg & 7) * 64 + (wg >> 3);
  const int bx = lid & 15, by = lid >> 4;
  const int brow = by * BM;
  const int bcol = bx * BN;

  i32x16 acc[4][2] = {};

  // ---- staging: sweep = 512 thr x 16B = 8KB = 128 rows x 64B; 2 sweeps per matrix ----
  const int srow = tid >> 2;                           // 0..127
  const int schunk = ((tid & 3) ^ (srow & 3)) * 16;    // pre-swizzled source chunk
  const int wub = (tid & ~63) * 16;                    // wave-uniform LDS base
  const char* gAs = A + (long)(brow + srow) * K_DIM + schunk;
  const char* gBs = B + (long)(bcol + srow) * K_DIM + schunk;

#define STAGE_A(T)                                                        \
  do {                                                                    \
    char* d = lds + ((T) & 3) * 32768;                                    \
    gload_lds16(gAs + (long)(T) * 64, d + wub);                           \
    gload_lds16(gAs + 524288 + (long)(T) * 64, d + 8192 + wub);           \
  } while (0)
#define STAGE_B(T)                                                        \
  do {                                                                    \
    char* d = lds + ((T) & 3) * 32768 + 16384;                            \
    gload_lds16(gBs + (long)(T) * 64, d + wub);                           \
    gload_lds16(gBs + 524288 + (long)(T) * 64, d + 8192 + wub);           \
  } while (0)

  // ---- fragment read offsets ----
  // 32x32x32 i8 operand: lane holds [row=lane&31][k = (lane>>5)*16 + 0..15].
  // k-chunk index = ks*2 + kg (ks in {0,1} halves of BK=64), XOR (row&3).
  const int row5 = lane & 31;
  const int kg = lane >> 5;
  int aoff[2], boff[2];
#pragma unroll
  for (int ks = 0; ks < 2; ++ks) {
    const int ch = ((ks * 2 + kg) ^ (row5 & 3)) * 16;
    aoff[ks] = (wr * 128 + row5) * 64 + ch;
    boff[ks] = (wc * 64 + row5) * 64 + ch;
  }

#define RD_A(BB, FM, KS) (*(const i32x4*)(lds + (BB) + aoff[KS] + (FM) * 2048))
#define RD_B(BB, FN, KS) (*(const i32x4*)(lds + (BB) + 16384 + boff[KS] + (FN) * 2048))
#define MMA(FM, FN, AV, BV)                                                   \
  acc[FM][FN] = __builtin_amdgcn_mfma_i32_32x32x32_i8(AV, BV, acc[FM][FN], 0, 0, 0)

#define BAR() __builtin_amdgcn_s_barrier()
#define VMC(N)                                                                \
  do {                                                                        \
    asm volatile("s_waitcnt vmcnt(" #N ")");                                  \
    __builtin_amdgcn_sched_barrier(0);                                        \
  } while (0)

  // ---- prologue: stage tiles 0 and 1 ----
  STAGE_A(0); STAGE_B(0);
  STAGE_A(1); STAGE_B(1);
  VMC(4);  // tile 0's 4 loads (oldest) landed; tile 1's may remain in flight
  BAR();

  i32x4 a00, a01, a10, a11, b00, b01, b10, b11;

  // ---- main loop: tiles 0..NT2-3, staging t+2 ----
  for (int t = 0; t < NT2 - 2; ++t) {
    const int bb = (t & 3) * 32768;
    // P0: fm {0,1}
    a00 = RD_A(bb, 0, 0); a01 = RD_A(bb, 0, 1);
    a10 = RD_A(bb, 1, 0); a11 = RD_A(bb, 1, 1);
    b00 = RD_B(bb, 0, 0); b01 = RD_B(bb, 0, 1);
    b10 = RD_B(bb, 1, 0); b11 = RD_B(bb, 1, 1);
    STAGE_A(t + 2);
    BAR();
    __builtin_amdgcn_s_setprio(1);
    MMA(0, 0, a00, b00); MMA(0, 1, a00, b10);
    MMA(1, 0, a10, b00); MMA(1, 1, a10, b10);
    MMA(0, 0, a01, b01); MMA(0, 1, a01, b11);
    MMA(1, 0, a11, b01); MMA(1, 1, a11, b11);
    __builtin_amdgcn_s_setprio(0);
    BAR();
    // P1: fm {2,3}
    a00 = RD_A(bb, 2, 0); a01 = RD_A(bb, 2, 1);
    a10 = RD_A(bb, 3, 0); a11 = RD_A(bb, 3, 1);
    STAGE_B(t + 2);
    BAR();
    __builtin_amdgcn_s_setprio(1);
    MMA(2, 0, a00, b00); MMA(2, 1, a00, b10);
    MMA(3, 0, a10, b00); MMA(3, 1, a10, b10);
    MMA(2, 0, a01, b01); MMA(2, 1, a01, b11);
    MMA(3, 0, a11, b01); MMA(3, 1, a11, b11);
    __builtin_amdgcn_s_setprio(0);
    VMC(4);  // forces tile t+1 (oldest 4) landed; t+2's 4 stay in flight
    BAR();
  }

  // ---- tail: tiles NT2-2 and NT2-1, no staging ----
#pragma unroll
  for (int tt = 0; tt < 2; ++tt) {
    const int t = NT2 - 2 + tt;
    const int bb = (t & 3) * 32768;
    a00 = RD_A(bb, 0, 0); a01 = RD_A(bb, 0, 1);
    a10 = RD_A(bb, 1, 0); a11 = RD_A(bb, 1, 1);
    b00 = RD_B(bb, 0, 0); b01 = RD_B(bb, 0, 1);
    b10 = RD_B(bb, 1, 0); b11 = RD_B(bb, 1, 1);
    MMA(0, 0, a00, b00); MMA(0, 1, a00, b10);
    MMA(1, 0, a10, b00); MMA(1, 1, a10, b10);
    MMA(0, 0, a01, b01); MMA(0, 1, a01, b11);
    MMA(1, 0, a11, b01); MMA(1, 1, a11, b11);
    a00 = RD_A(bb, 2, 0); a01 = RD_A(bb, 2, 1);
    a10 = RD_A(bb, 3, 0); a11 = RD_A(bb, 3, 1);
    MMA(2, 0, a00, b00); MMA(2, 1, a00, b10);
    MMA(3, 0, a10, b00); MMA(3, 1, a10, b10);
    MMA(2, 0, a01, b01); MMA(2, 1, a01, b11);
    MMA(3, 0, a11, b01); MMA(3, 1, a11, b11);
    if (tt == 0) { VMC(0); BAR(); }  // last tile fully landed
  }

  // ---- epilogue: C/D layout col=lane&31, row=(r&3)+8*(r>>2)+4*kg (dtype-indep) ----
  // y = s * rx * (dot_i32 + (128 - zp) * sum_xi) + b
  float sc[2], zp[2], bs[2];
  int coln[2];
#pragma unroll
  for (int fn = 0; fn < 2; ++fn) {
    coln[fn] = bcol + wc * 64 + fn * 32 + row5;
    sc[fn] = scales[coln[fn]];
    zp[fn] = 128.f - zps[coln[fn]];
    bs[fn] = bias[coln[fn]];
  }
#pragma unroll
  for (int fm = 0; fm < 4; ++fm) {
#pragma unroll
    for (int r = 0; r < 16; ++r) {
      const int grow = brow + wr * 128 + fm * 32 + (r & 3) + 8 * (r >> 2) + 4 * kg;
      const float rxv = rx[grow];
      const float sxv = sxf[grow];
#pragma unroll
      for (int fn = 0; fn < 2; ++fn) {
        C[(long)grow * N_DIM + coln[fn]] =
            sc[fn] * rxv * ((float)acc[fm][fn][r] + zp[fn] * sxv) + bs[fn];
      }
    }
  }
}

// ---------------- launch ----------------
extern "C" void kernel_launch(void* const* d_in, const int* in_sizes, int n_in,
                              void* d_out, int out_size, void* d_ws, size_t ws_size,
                              hipStream_t stream) {
  const float* x = (const float*)d_in[0];
  const int* qw = (const int*)d_in[1];
  const float* scales = (const float*)d_in[2];
  const float* zps = (const float*)d_in[3];
  const float* bias = (const float*)d_in[4];
  float* out = (float*)d_out;

  char* ws = (char*)d_ws;
  char* xq = ws;                                             // 32 MB i8
  char* qb = ws + (size_t)32 * 1024 * 1024;                  // 16 MB i8
  float* rx = (float*)(ws + (size_t)48 * 1024 * 1024);       // 32 KB
  float* sxf = (float*)(ws + (size_t)48 * 1024 * 1024 + 65536);  // 32 KB

  hipLaunchKernelGGL(prep_x_i8, dim3(M_DIM), dim3(256), 0, stream, x, xq, rx, sxf);
  hipLaunchKernelGGL(prep_q_i8, dim3((N_DIM * K_DIM / 4) / 256), dim3(256), 0, stream,
                     qw, qb);
  hipLaunchKernelGGL(wq_gemm_i8, dim3((M_DIM / BM) * (N_DIM / BN)), dim3(512), 0,
                     stream, xq, qb, rx, sxf, scales, zps, bias, out);
}

// Round 8
// 195.452 us; speedup vs baseline: 1.5634x; 1.1032x over previous
//
#include <hip/hip_runtime.h>
#include <hip/hip_bf16.h>

// ---------------- common ----------------
typedef __attribute__((ext_vector_type(4))) int i32x4;
typedef __attribute__((ext_vector_type(16))) int i32x16;

#define M_DIM 8192
#define N_DIM 4096
#define K_DIM 4096
#define BM 256
#define BN 256
#define BK 128
#define NT2 (K_DIM / BK)  // 32

static __device__ inline void gload_lds16(const void* g, void* l) {
  __builtin_amdgcn_global_load_lds(
      (const __attribute__((address_space(1))) unsigned int*)g,
      (__attribute__((address_space(3))) unsigned int*)l,
      16, 0, 0);
}

// ---------------- prep: x fp32 -> i8 (per-row symmetric), row scale + int row-sum ----------------
__global__ __launch_bounds__(256) void prep_x_i8(
    const float* __restrict__ x, char* __restrict__ xq,
    float* __restrict__ rx, float* __restrict__ sxf) {
  const int row = blockIdx.x;
  const int tid = threadIdx.x;
  const float4* xr = (const float4*)(x + (long)row * K_DIM);
  float4 v[4];
  float mx = 0.f;
#pragma unroll
  for (int i = 0; i < 4; ++i) {
    v[i] = xr[i * 256 + tid];
    mx = fmaxf(mx, fmaxf(fmaxf(fabsf(v[i].x), fabsf(v[i].y)),
                         fmaxf(fabsf(v[i].z), fabsf(v[i].w))));
  }
#pragma unroll
  for (int off = 32; off > 0; off >>= 1) mx = fmaxf(mx, __shfl_down(mx, off, 64));
  __shared__ float redm[4];
  __shared__ int reds[4];
  const int lane = tid & 63, w = tid >> 6;
  if (lane == 0) redm[w] = mx;
  __syncthreads();
  const float maxv = fmaxf(fmaxf(redm[0], redm[1]), fmaxf(redm[2], redm[3]));
  const float inv = maxv > 0.f ? 127.f / maxv : 0.f;
  int* xo = (int*)(xq + (long)row * K_DIM);
  int ssum = 0;
#pragma unroll
  for (int i = 0; i < 4; ++i) {
    const int q0 = __float2int_rn(v[i].x * inv);
    const int q1 = __float2int_rn(v[i].y * inv);
    const int q2 = __float2int_rn(v[i].z * inv);
    const int q3 = __float2int_rn(v[i].w * inv);
    ssum += q0 + q1 + q2 + q3;
    xo[i * 256 + tid] =
        (q0 & 255) | ((q1 & 255) << 8) | ((q2 & 255) << 16) | ((q3 & 255) << 24);
  }
#pragma unroll
  for (int off = 32; off > 0; off >>= 1) ssum += __shfl_down(ssum, off, 64);
  if (lane == 0) reds[w] = ssum;
  __syncthreads();
  if (tid == 0) {
    rx[row] = maxv * (1.f / 127.f);
    sxf[row] = (float)(reds[0] + reds[1] + reds[2] + reds[3]);
  }
}

// ---------------- prep: qweight int32 [0,255] -> i8 (q-128), exact ----------------
__global__ __launch_bounds__(256) void prep_q_i8(
    const int* __restrict__ q, char* __restrict__ qb) {
  const long idx = (long)blockIdx.x * blockDim.x + threadIdx.x;  // one int4 -> one int
  const int4 v = ((const int4*)q)[idx];
  const int a = v.x - 128, b = v.y - 128, c = v.z - 128, d = v.w - 128;
  ((int*)qb)[idx] = (a & 255) | ((b & 255) << 8) | ((c & 255) << 16) | ((d & 255) << 24);
}

// ---------------- GEMM: 256x256, BK=128 (128B rows), i8 32x32x32 MFMA ----------------
// Geometry identical (in bytes) to the conflict-free bf16 R5 layout: rows are 128B =
// 8 chunks of 16B, chunk swizzle c_src = c ^ (row&7) on the pre-swizzled global source
// (LDS dest linear per global_load_lds) and the same XOR on the read side (rule #21).
// 8 waves (2Mx4N); wave tile 128x64 = 4 fm x 2 fn (32x32 frags), 4 ks per tile.
// Per K-tile per wave: 32 MFMA + 24 ds_read_b128. Double-buffered 2x64KB = 128 KiB.
// Ledger (steady state, verified): stage order for tile t+1 across phases:
//   P0:{A0,A2} P1:{B0,B2} P2:{B1,B3} P3:{A1,A3}
//   P0/P1 read A sweeps {2wr} in {0,2} + B sweep wc; P2/P3 read A sweeps {2wr+1} in {1,3}.
//   VMC(4) before P2 forces prev {A1,A3}; VMC(2) at boundary forces t+1's all-B + {A0,A2}.
__global__ __launch_bounds__(512, 2) void wq_gemm_i8(
    const char* __restrict__ A,             // xq [M][K] i8
    const char* __restrict__ B,             // qb [N][K] i8
    const float* __restrict__ rx,           // [M] row scale
    const float* __restrict__ sxf,          // [M] sum of xi (float, exact)
    const float* __restrict__ scales,       // [N]
    const float* __restrict__ zps,          // [N]
    const float* __restrict__ bias,         // [N]
    float* __restrict__ C) {                // [M][N]
  __shared__ __align__(16) char lds[2 * 65536];  // [buf][A:32KB | B:32KB]

  const int tid = threadIdx.x;
  const int lane = tid & 63;
  const int wv = tid >> 6;
  const int wr = wv >> 2, wc = wv & 3;

  // T1: XCD-aware chunked swizzle (nwg=512, 512%8==0).
  const int wg = blockIdx.x;
  const int lid = (wg & 7) * 64 + (wg >> 3);
  const int bx = lid & 15, by = lid >> 4;
  const int brow = by * BM;
  const int bcol = bx * BN;

  i32x16 acc[4][2] = {};

  // ---- staging: sweep = 512 thr x 16B = 8KB = 64 rows x 128B; 4 sweeps per matrix ----
  const int srow = tid >> 3;                           // 0..63 within sweep
  const int schunk = ((tid & 7) ^ (srow & 7)) * 16;    // pre-swizzled source chunk
  const int wub = (tid & ~63) * 16;                    // wave-uniform LDS base
  const char* gAs = A + (long)(brow + srow) * K_DIM + schunk;
  const char* gBs = B + (long)(bcol + srow) * K_DIM + schunk;

  // sweep j covers rows j*64..j*64+63 -> global + j*64*K_DIM; tile t -> + t*128 bytes.
#define STAGE_A2(T, J0, J1)                                                   \
  do {                                                                        \
    char* d = lds + ((T) & 1) * 65536;                                        \
    gload_lds16(gAs + (long)(J0) * 262144 + (long)(T) * 128,                  \
                d + (J0) * 8192 + wub);                                       \
    gload_lds16(gAs + (long)(J1) * 262144 + (long)(T) * 128,                  \
                d + (J1) * 8192 + wub);                                       \
  } while (0)
#define STAGE_B2(T, J0, J1)                                                   \
  do {                                                                        \
    char* d = lds + ((T) & 1) * 65536 + 32768;                                \
    gload_lds16(gBs + (long)(J0) * 262144 + (long)(T) * 128,                  \
                d + (J0) * 8192 + wub);                                       \
    gload_lds16(gBs + (long)(J1) * 262144 + (long)(T) * 128,                  \
                d + (J1) * 8192 + wub);                                       \
  } while (0)

  // ---- fragment read offsets ----
  // 32x32x32 i8 operand: lane holds [row=lane&31][k = kg*16 + 0..15], kg=lane>>5.
  // Within a 128B row: chunk(ks) = ks*2 + kg (ks=0..3), swizzled by XOR (row&7).
  const int row5 = lane & 31;
  const int kg = lane >> 5;
  int aoff[4], boff[4];
#pragma unroll
  for (int ks = 0; ks < 4; ++ks) {
    const int ch = ((ks * 2 + kg) ^ (row5 & 7)) * 16;
    aoff[ks] = (wr * 128 + row5) * 128 + ch;
    boff[ks] = (wc * 64 + row5) * 128 + ch;
  }

#define RD_A(BB, FM, KS) (*(const i32x4*)(lds + (BB) + aoff[KS] + (FM) * 4096))
#define RD_B(BB, FN, KS) (*(const i32x4*)(lds + (BB) + 32768 + boff[KS] + (FN) * 4096))
#define MMA(FM, FN, AV, BV)                                                   \
  acc[FM][FN] = __builtin_amdgcn_mfma_i32_32x32x32_i8(AV, BV, acc[FM][FN], 0, 0, 0)

#define BAR() __builtin_amdgcn_s_barrier()
#define VMC(N)                                                                \
  do {                                                                        \
    asm volatile("s_waitcnt vmcnt(" #N ")");                                  \
    __builtin_amdgcn_sched_barrier(0);                                        \
  } while (0)

  // ---- prologue: full stage of tile 0 into buf0 (ledger order) ----
  STAGE_A2(0, 0, 2);
  STAGE_B2(0, 0, 2);
  STAGE_B2(0, 1, 3);
  STAGE_A2(0, 1, 3);
  VMC(2);  // all of tile 0 except its {A1,A3} landed (they land before P2's VMC(4))
  BAR();

  i32x4 a00, a01, a10, a11, b00, b10, b01, b11, b02, b12, b03, b13;

  // ---- main loop: tiles 0..NT2-2, staging t+1 into other buf ----
  for (int t = 0; t < NT2 - 1; ++t) {
    const int bb = (t & 1) * 65536;
    const int t1 = t + 1;
    // P0: fm {0,1} x ks {0,1}
    a00 = RD_A(bb, 0, 0); a10 = RD_A(bb, 1, 0);
    a01 = RD_A(bb, 0, 1); a11 = RD_A(bb, 1, 1);
    b00 = RD_B(bb, 0, 0); b10 = RD_B(bb, 1, 0);
    b01 = RD_B(bb, 0, 1); b11 = RD_B(bb, 1, 1);
    STAGE_A2(t1, 0, 2);
    BAR();
    __builtin_amdgcn_s_setprio(1);
    MMA(0, 0, a00, b00); MMA(0, 1, a00, b10);
    MMA(1, 0, a10, b00); MMA(1, 1, a10, b10);
    MMA(0, 0, a01, b01); MMA(0, 1, a01, b11);
    MMA(1, 0, a11, b01); MMA(1, 1, a11, b11);
    __builtin_amdgcn_s_setprio(0);
    BAR();
    // P1: fm {0,1} x ks {2,3}
    a00 = RD_A(bb, 0, 2); a10 = RD_A(bb, 1, 2);
    a01 = RD_A(bb, 0, 3); a11 = RD_A(bb, 1, 3);
    b02 = RD_B(bb, 0, 2); b12 = RD_B(bb, 1, 2);
    b03 = RD_B(bb, 0, 3); b13 = RD_B(bb, 1, 3);
    STAGE_B2(t1, 0, 2);
    BAR();
    __builtin_amdgcn_s_setprio(1);
    MMA(0, 0, a00, b02); MMA(0, 1, a00, b12);
    MMA(1, 0, a10, b02); MMA(1, 1, a10, b12);
    MMA(0, 0, a01, b03); MMA(0, 1, a01, b13);
    MMA(1, 0, a11, b03); MMA(1, 1, a11, b13);
    __builtin_amdgcn_s_setprio(0);
    VMC(4);  // prev {A1,A3} landed -> P2/P3 A-sweep-{1,3} reads safe
    BAR();
    // P2: fm {2,3} x ks {0,1}
    a00 = RD_A(bb, 2, 0); a10 = RD_A(bb, 3, 0);
    a01 = RD_A(bb, 2, 1); a11 = RD_A(bb, 3, 1);
    STAGE_B2(t1, 1, 3);
    BAR();
    __builtin_amdgcn_s_setprio(1);
    MMA(2, 0, a00, b00); MMA(2, 1, a00, b10);
    MMA(3, 0, a10, b00); MMA(3, 1, a10, b10);
    MMA(2, 0, a01, b01); MMA(2, 1, a01, b11);
    MMA(3, 0, a11, b01); MMA(3, 1, a11, b11);
    __builtin_amdgcn_s_setprio(0);
    BAR();
    // P3: fm {2,3} x ks {2,3}
    a00 = RD_A(bb, 2, 2); a10 = RD_A(bb, 3, 2);
    a01 = RD_A(bb, 2, 3); a11 = RD_A(bb, 3, 3);
    STAGE_A2(t1, 1, 3);
    BAR();
    __builtin_amdgcn_s_setprio(1);
    MMA(2, 0, a00, b02); MMA(2, 1, a00, b12);
    MMA(3, 0, a10, b02); MMA(3, 1, a10, b12);
    MMA(2, 0, a01, b03); MMA(2, 1, a01, b13);
    MMA(3, 0, a11, b03); MMA(3, 1, a11, b13);
    __builtin_amdgcn_s_setprio(0);
    VMC(2);  // tile t+1: all B + A{0,2} landed -> next P0/P1 safe
    BAR();
  }

  // ---- tail: tile NT2-1 (odd -> buf1), no staging ----
  {
    const int bb = 65536;
    a00 = RD_A(bb, 0, 0); a10 = RD_A(bb, 1, 0);
    a01 = RD_A(bb, 0, 1); a11 = RD_A(bb, 1, 1);
    b00 = RD_B(bb, 0, 0); b10 = RD_B(bb, 1, 0);
    b01 = RD_B(bb, 0, 1); b11 = RD_B(bb, 1, 1);
    MMA(0, 0, a00, b00); MMA(0, 1, a00, b10);
    MMA(1, 0, a10, b00); MMA(1, 1, a10, b10);
    MMA(0, 0, a01, b01); MMA(0, 1, a01, b11);
    MMA(1, 0, a11, b01); MMA(1, 1, a11, b11);
    a00 = RD_A(bb, 0, 2); a10 = RD_A(bb, 1, 2);
    a01 = RD_A(bb, 0, 3); a11 = RD_A(bb, 1, 3);
    b02 = RD_B(bb, 0, 2); b12 = RD_B(bb, 1, 2);
    b03 = RD_B(bb, 0, 3); b13 = RD_B(bb, 1, 3);
    MMA(0, 0, a00, b02); MMA(0, 1, a00, b12);
    MMA(1, 0, a10, b02); MMA(1, 1, a10, b12);
    MMA(0, 0, a01, b03); MMA(0, 1, a01, b13);
    MMA(1, 0, a11, b03); MMA(1, 1, a11, b13);
    VMC(0);  // drain tile's {A1,A3}
    BAR();
    a00 = RD_A(bb, 2, 0); a10 = RD_A(bb, 3, 0);
    a01 = RD_A(bb, 2, 1); a11 = RD_A(bb, 3, 1);
    MMA(2, 0, a00, b00); MMA(2, 1, a00, b10);
    MMA(3, 0, a10, b00); MMA(3, 1, a10, b10);
    MMA(2, 0, a01, b01); MMA(2, 1, a01, b11);
    MMA(3, 0, a11, b01); MMA(3, 1, a11, b11);
    a00 = RD_A(bb, 2, 2); a10 = RD_A(bb, 3, 2);
    a01 = RD_A(bb, 2, 3); a11 = RD_A(bb, 3, 3);
    MMA(2, 0, a00, b02); MMA(2, 1, a00, b12);
    MMA(3, 0, a10, b02); MMA(3, 1, a10, b12);
    MMA(2, 0, a01, b03); MMA(2, 1, a01, b13);
    MMA(3, 0, a11, b03); MMA(3, 1, a11, b13);
  }

  // ---- epilogue: C/D layout col=lane&31, row=(r&3)+8*(r>>2)+4*kg (dtype-indep) ----
  // y = s * rx * (dot_i32 + (128 - zp) * sum_xi) + b
  float sc[2], zp[2], bs[2];
  int coln[2];
#pragma unroll
  for (int fn = 0; fn < 2; ++fn) {
    coln[fn] = bcol + wc * 64 + fn * 32 + row5;
    sc[fn] = scales[coln[fn]];
    zp[fn] = 128.f - zps[coln[fn]];
    bs[fn] = bias[coln[fn]];
  }
#pragma unroll
  for (int fm = 0; fm < 4; ++fm) {
#pragma unroll
    for (int r = 0; r < 16; ++r) {
      const int grow = brow + wr * 128 + fm * 32 + (r & 3) + 8 * (r >> 2) + 4 * kg;
      const float rxv = rx[grow];
      const float sxv = sxf[grow];
#pragma unroll
      for (int fn = 0; fn < 2; ++fn) {
        C[(long)grow * N_DIM + coln[fn]] =
            sc[fn] * rxv * ((float)acc[fm][fn][r] + zp[fn] * sxv) + bs[fn];
      }
    }
  }
}

// ---------------- launch ----------------
extern "C" void kernel_launch(void* const* d_in, const int* in_sizes, int n_in,
                              void* d_out, int out_size, void* d_ws, size_t ws_size,
                              hipStream_t stream) {
  const float* x = (const float*)d_in[0];
  const int* qw = (const int*)d_in[1];
  const float* scales = (const float*)d_in[2];
  const float* zps = (const float*)d_in[3];
  const float* bias = (const float*)d_in[4];
  float* out = (float*)d_out;

  char* ws = (char*)d_ws;
  char* xq = ws;                                             // 32 MB i8
  char* qb = ws + (size_t)32 * 1024 * 1024;                  // 16 MB i8
  float* rx = (float*)(ws + (size_t)48 * 1024 * 1024);       // 32 KB
  float* sxf = (float*)(ws + (size_t)48 * 1024 * 1024 + 65536);  // 32 KB

  hipLaunchKernelGGL(prep_x_i8, dim3(M_DIM), dim3(256), 0, stream, x, xq, rx, sxf);
  hipLaunchKernelGGL(prep_q_i8, dim3((N_DIM * K_DIM / 4) / 256), dim3(256), 0, stream,
                     qw, qb);
  hipLaunchKernelGGL(wq_gemm_i8, dim3((M_DIM / BM) * (N_DIM / BN)), dim3(512), 0,
                     stream, xq, qb, rx, sxf, scales, zps, bias, out);
}

// Round 9
// 192.675 us; speedup vs baseline: 1.5860x; 1.0144x over previous
//
#include <hip/hip_runtime.h>
#include <hip/hip_bf16.h>

// ---------------- common ----------------
typedef __attribute__((ext_vector_type(4))) int i32x4;
typedef __attribute__((ext_vector_type(16))) int i32x16;

#define M_DIM 8192
#define N_DIM 4096
#define K_DIM 4096
#define BM 256
#define BN 256
#define BK 128
#define NT2 (K_DIM / BK)  // 32

static __device__ inline void gload_lds16(const void* g, void* l) {
  __builtin_amdgcn_global_load_lds(
      (const __attribute__((address_space(1))) unsigned int*)g,
      (__attribute__((address_space(3))) unsigned int*)l,
      16, 0, 0);
}

// ---------------- prep: x fp32 -> i8 (per-row symmetric), row scale + int row-sum ----------------
__global__ __launch_bounds__(256) void prep_x_i8(
    const float* __restrict__ x, char* __restrict__ xq,
    float* __restrict__ rx, float* __restrict__ sxf) {
  const int row = blockIdx.x;
  const int tid = threadIdx.x;
  const float4* xr = (const float4*)(x + (long)row * K_DIM);
  float4 v[4];
  float mx = 0.f;
#pragma unroll
  for (int i = 0; i < 4; ++i) {
    v[i] = xr[i * 256 + tid];
    mx = fmaxf(mx, fmaxf(fmaxf(fabsf(v[i].x), fabsf(v[i].y)),
                         fmaxf(fabsf(v[i].z), fabsf(v[i].w))));
  }
#pragma unroll
  for (int off = 32; off > 0; off >>= 1) mx = fmaxf(mx, __shfl_down(mx, off, 64));
  __shared__ float redm[4];
  __shared__ int reds[4];
  const int lane = tid & 63, w = tid >> 6;
  if (lane == 0) redm[w] = mx;
  __syncthreads();
  const float maxv = fmaxf(fmaxf(redm[0], redm[1]), fmaxf(redm[2], redm[3]));
  const float inv = maxv > 0.f ? 127.f / maxv : 0.f;
  int* xo = (int*)(xq + (long)row * K_DIM);
  int ssum = 0;
#pragma unroll
  for (int i = 0; i < 4; ++i) {
    const int q0 = __float2int_rn(v[i].x * inv);
    const int q1 = __float2int_rn(v[i].y * inv);
    const int q2 = __float2int_rn(v[i].z * inv);
    const int q3 = __float2int_rn(v[i].w * inv);
    ssum += q0 + q1 + q2 + q3;
    xo[i * 256 + tid] =
        (q0 & 255) | ((q1 & 255) << 8) | ((q2 & 255) << 16) | ((q3 & 255) << 24);
  }
#pragma unroll
  for (int off = 32; off > 0; off >>= 1) ssum += __shfl_down(ssum, off, 64);
  if (lane == 0) reds[w] = ssum;
  __syncthreads();
  if (tid == 0) {
    rx[row] = maxv * (1.f / 127.f);
    sxf[row] = (float)(reds[0] + reds[1] + reds[2] + reds[3]);
  }
}

// ---------------- prep: qweight int32 [0,255] -> i8 (q-128), exact ----------------
__global__ __launch_bounds__(256) void prep_q_i8(
    const int* __restrict__ q, char* __restrict__ qb) {
  const long idx = (long)blockIdx.x * blockDim.x + threadIdx.x;  // one int4 -> one int
  const int4 v = ((const int4*)q)[idx];
  const int a = v.x - 128, b = v.y - 128, c = v.z - 128, d = v.w - 128;
  ((int*)qb)[idx] = (a & 255) | ((b & 255) << 8) | ((c & 255) << 16) | ((d & 255) << 24);
}

// ---------------- GEMM: 256x256, BK=128 (128B rows), i8 32x32x32 MFMA ----------------
// R8 geometry (conflict-free 128B rows, XOR-(row&7) chunk swizzle both-sides) with the
// lockstep removed: only the 2 PROTECTIVE sync points per K-tile survive (collective
// counted-vmcnt + barrier); the 6 pacing barriers are gone so the 2 waves/SIMD drift
// into read/MFMA ping-pong.
// Ledger (steady state): per tile t we issue G1(t+1) = {A0,A2,B0,B2,B1,B3} (6 loads)
// in the first half and G2(t+1) = {A1,A3} (2 loads) in the second half.
//   mid-tile:  outstanding = G2(t) (2) + G1(t+1) (6) -> VMC(6) forces G2(t) landed
//              (second half reads A sweeps {1,3} of tile t)
//   boundary:  outstanding = G1(t+1) + G2(t+1) -> VMC(2) forces G1(t+1) landed
//              (next first half reads A{0,2} + all B of tile t+1)
// Buffer safety: all reads of a half are consumed by that half's MFMAs (compiler
// emits lgkmcnt before them), so reads are complete before each barrier.
__global__ __launch_bounds__(512, 2) void wq_gemm_i8(
    const char* __restrict__ A,             // xq [M][K] i8
    const char* __restrict__ B,             // qb [N][K] i8
    const float* __restrict__ rx,           // [M] row scale
    const float* __restrict__ sxf,          // [M] sum of xi (float, exact)
    const float* __restrict__ scales,       // [N]
    const float* __restrict__ zps,          // [N]
    const float* __restrict__ bias,         // [N]
    float* __restrict__ C) {                // [M][N]
  __shared__ __align__(16) char lds[2 * 65536];  // [buf][A:32KB | B:32KB]

  const int tid = threadIdx.x;
  const int lane = tid & 63;
  const int wv = tid >> 6;
  const int wr = wv >> 2, wc = wv & 3;

  // T1: XCD-aware chunked swizzle (nwg=512, 512%8==0).
  const int wg = blockIdx.x;
  const int lid = (wg & 7) * 64 + (wg >> 3);
  const int bx = lid & 15, by = lid >> 4;
  const int brow = by * BM;
  const int bcol = bx * BN;

  i32x16 acc[4][2] = {};

  // ---- staging: sweep = 512 thr x 16B = 8KB = 64 rows x 128B; 4 sweeps per matrix ----
  const int srow = tid >> 3;                           // 0..63 within sweep
  const int schunk = ((tid & 7) ^ (srow & 7)) * 16;    // pre-swizzled source chunk
  const int wub = (tid & ~63) * 16;                    // wave-uniform LDS base
  const char* gAs = A + (long)(brow + srow) * K_DIM + schunk;
  const char* gBs = B + (long)(bcol + srow) * K_DIM + schunk;

  // sweep j covers rows j*64..j*64+63 -> global + j*64*K_DIM; tile t -> + t*128 bytes.
#define STAGE_A2(T, J0, J1)                                                   \
  do {                                                                        \
    char* d = lds + ((T) & 1) * 65536;                                        \
    gload_lds16(gAs + (long)(J0) * 262144 + (long)(T) * 128,                  \
                d + (J0) * 8192 + wub);                                       \
    gload_lds16(gAs + (long)(J1) * 262144 + (long)(T) * 128,                  \
                d + (J1) * 8192 + wub);                                       \
  } while (0)
#define STAGE_B2(T, J0, J1)                                                   \
  do {                                                                        \
    char* d = lds + ((T) & 1) * 65536 + 32768;                                \
    gload_lds16(gBs + (long)(J0) * 262144 + (long)(T) * 128,                  \
                d + (J0) * 8192 + wub);                                       \
    gload_lds16(gBs + (long)(J1) * 262144 + (long)(T) * 128,                  \
                d + (J1) * 8192 + wub);                                       \
  } while (0)

  // ---- fragment read offsets ----
  // 32x32x32 i8 operand: lane holds [row=lane&31][k = kg*16 + 0..15], kg=lane>>5.
  // Within a 128B row: chunk(ks) = ks*2 + kg (ks=0..3), swizzled by XOR (row&7).
  const int row5 = lane & 31;
  const int kg = lane >> 5;
  int aoff[4], boff[4];
#pragma unroll
  for (int ks = 0; ks < 4; ++ks) {
    const int ch = ((ks * 2 + kg) ^ (row5 & 7)) * 16;
    aoff[ks] = (wr * 128 + row5) * 128 + ch;
    boff[ks] = (wc * 64 + row5) * 128 + ch;
  }

#define RD_A(BB, FM, KS) (*(const i32x4*)(lds + (BB) + aoff[KS] + (FM) * 4096))
#define RD_B(BB, FN, KS) (*(const i32x4*)(lds + (BB) + 32768 + boff[KS] + (FN) * 4096))
#define MMA(FM, FN, AV, BV)                                                   \
  acc[FM][FN] = __builtin_amdgcn_mfma_i32_32x32x32_i8(AV, BV, acc[FM][FN], 0, 0, 0)

#define BAR() __builtin_amdgcn_s_barrier()
#define VMC(N)                                                                \
  do {                                                                        \
    asm volatile("s_waitcnt vmcnt(" #N ")");                                  \
    __builtin_amdgcn_sched_barrier(0);                                        \
  } while (0)

  // ---- prologue: stage tile 0 into buf0 (G1 then G2 order) ----
  STAGE_A2(0, 0, 2);
  STAGE_B2(0, 0, 2);
  STAGE_B2(0, 1, 3);
  STAGE_A2(0, 1, 3);
  VMC(2);  // G1(0) landed; G2(0)={A1,A3} may fly until mid-tile VMC
  BAR();

  i32x4 a00, a01, a10, a11, a20, a21, a30, a31;
  i32x4 b00, b10, b01, b11, b02, b12, b03, b13;

  // ---- main loop: tiles 0..NT2-2, staging t+1 into other buf ----
  for (int t = 0; t < NT2 - 1; ++t) {
    const int bb = (t & 1) * 65536;
    const int t1 = t + 1;
    // ---- first half: fm {0,1} x all ks ----
    a00 = RD_A(bb, 0, 0); a10 = RD_A(bb, 1, 0);
    a01 = RD_A(bb, 0, 1); a11 = RD_A(bb, 1, 1);
    a20 = RD_A(bb, 0, 2); a30 = RD_A(bb, 1, 2);
    a21 = RD_A(bb, 0, 3); a31 = RD_A(bb, 1, 3);
    b00 = RD_B(bb, 0, 0); b10 = RD_B(bb, 1, 0);
    b01 = RD_B(bb, 0, 1); b11 = RD_B(bb, 1, 1);
    b02 = RD_B(bb, 0, 2); b12 = RD_B(bb, 1, 2);
    b03 = RD_B(bb, 0, 3); b13 = RD_B(bb, 1, 3);
    STAGE_A2(t1, 0, 2);      // G1(t+1): 6 loads
    STAGE_B2(t1, 0, 2);
    STAGE_B2(t1, 1, 3);
    __builtin_amdgcn_s_setprio(1);
    MMA(0, 0, a00, b00); MMA(0, 1, a00, b10);
    MMA(1, 0, a10, b00); MMA(1, 1, a10, b10);
    MMA(0, 0, a01, b01); MMA(0, 1, a01, b11);
    MMA(1, 0, a11, b01); MMA(1, 1, a11, b11);
    MMA(0, 0, a20, b02); MMA(0, 1, a20, b12);
    MMA(1, 0, a30, b02); MMA(1, 1, a30, b12);
    MMA(0, 0, a21, b03); MMA(0, 1, a21, b13);
    MMA(1, 0, a31, b03); MMA(1, 1, a31, b13);
    __builtin_amdgcn_s_setprio(0);
    VMC(6);  // G2(t)={A1,A3} landed -> second-half A-sweep-{1,3} reads safe
    BAR();
    // ---- second half: fm {2,3} x all ks ----
    a00 = RD_A(bb, 2, 0); a10 = RD_A(bb, 3, 0);
    a01 = RD_A(bb, 2, 1); a11 = RD_A(bb, 3, 1);
    a20 = RD_A(bb, 2, 2); a30 = RD_A(bb, 3, 2);
    a21 = RD_A(bb, 2, 3); a31 = RD_A(bb, 3, 3);
    STAGE_A2(t1, 1, 3);      // G2(t+1): 2 loads
    __builtin_amdgcn_s_setprio(1);
    MMA(2, 0, a00, b00); MMA(2, 1, a00, b10);
    MMA(3, 0, a10, b00); MMA(3, 1, a10, b10);
    MMA(2, 0, a01, b01); MMA(2, 1, a01, b11);
    MMA(3, 0, a11, b01); MMA(3, 1, a11, b11);
    MMA(2, 0, a20, b02); MMA(2, 1, a20, b12);
    MMA(3, 0, a30, b02); MMA(3, 1, a30, b12);
    MMA(2, 0, a21, b03); MMA(2, 1, a21, b13);
    MMA(3, 0, a31, b03); MMA(3, 1, a31, b13);
    __builtin_amdgcn_s_setprio(0);
    VMC(2);  // G1(t+1) landed -> next first half safe (G2(t+1) may fly)
    BAR();
  }

  // ---- tail: tile NT2-1 (odd -> buf1), no staging ----
  {
    const int bb = 65536;
    a00 = RD_A(bb, 0, 0); a10 = RD_A(bb, 1, 0);
    a01 = RD_A(bb, 0, 1); a11 = RD_A(bb, 1, 1);
    a20 = RD_A(bb, 0, 2); a30 = RD_A(bb, 1, 2);
    a21 = RD_A(bb, 0, 3); a31 = RD_A(bb, 1, 3);
    b00 = RD_B(bb, 0, 0); b10 = RD_B(bb, 1, 0);
    b01 = RD_B(bb, 0, 1); b11 = RD_B(bb, 1, 1);
    b02 = RD_B(bb, 0, 2); b12 = RD_B(bb, 1, 2);
    b03 = RD_B(bb, 0, 3); b13 = RD_B(bb, 1, 3);
    MMA(0, 0, a00, b00); MMA(0, 1, a00, b10);
    MMA(1, 0, a10, b00); MMA(1, 1, a10, b10);
    MMA(0, 0, a01, b01); MMA(0, 1, a01, b11);
    MMA(1, 0, a11, b01); MMA(1, 1, a11, b11);
    MMA(0, 0, a20, b02); MMA(0, 1, a20, b12);
    MMA(1, 0, a30, b02); MMA(1, 1, a30, b12);
    MMA(0, 0, a21, b03); MMA(0, 1, a21, b13);
    MMA(1, 0, a31, b03); MMA(1, 1, a31, b13);
    VMC(0);  // drain this tile's {A1,A3}
    BAR();
    a00 = RD_A(bb, 2, 0); a10 = RD_A(bb, 3, 0);
    a01 = RD_A(bb, 2, 1); a11 = RD_A(bb, 3, 1);
    a20 = RD_A(bb, 2, 2); a30 = RD_A(bb, 3, 2);
    a21 = RD_A(bb, 2, 3); a31 = RD_A(bb, 3, 3);
    MMA(2, 0, a00, b00); MMA(2, 1, a00, b10);
    MMA(3, 0, a10, b00); MMA(3, 1, a10, b10);
    MMA(2, 0, a01, b01); MMA(2, 1, a01, b11);
    MMA(3, 0, a11, b01); MMA(3, 1, a11, b11);
    MMA(2, 0, a20, b02); MMA(2, 1, a20, b12);
    MMA(3, 0, a30, b02); MMA(3, 1, a30, b12);
    MMA(2, 0, a21, b03); MMA(2, 1, a21, b13);
    MMA(3, 0, a31, b03); MMA(3, 1, a31, b13);
  }

  // ---- epilogue: C/D layout col=lane&31, row=(r&3)+8*(r>>2)+4*kg (dtype-indep) ----
  // y = s * rx * (dot_i32 + (128 - zp) * sum_xi) + b
  float sc[2], zp[2], bs[2];
  int coln[2];
#pragma unroll
  for (int fn = 0; fn < 2; ++fn) {
    coln[fn] = bcol + wc * 64 + fn * 32 + row5;
    sc[fn] = scales[coln[fn]];
    zp[fn] = 128.f - zps[coln[fn]];
    bs[fn] = bias[coln[fn]];
  }
#pragma unroll
  for (int fm = 0; fm < 4; ++fm) {
#pragma unroll
    for (int r = 0; r < 16; ++r) {
      const int grow = brow + wr * 128 + fm * 32 + (r & 3) + 8 * (r >> 2) + 4 * kg;
      const float rxv = rx[grow];
      const float sxv = sxf[grow];
#pragma unroll
      for (int fn = 0; fn < 2; ++fn) {
        C[(long)grow * N_DIM + coln[fn]] =
            sc[fn] * rxv * ((float)acc[fm][fn][r] + zp[fn] * sxv) + bs[fn];
      }
    }
  }
}

// ---------------- launch ----------------
extern "C" void kernel_launch(void* const* d_in, const int* in_sizes, int n_in,
                              void* d_out, int out_size, void* d_ws, size_t ws_size,
                              hipStream_t stream) {
  const float* x = (const float*)d_in[0];
  const int* qw = (const int*)d_in[1];
  const float* scales = (const float*)d_in[2];
  const float* zps = (const float*)d_in[3];
  const float* bias = (const float*)d_in[4];
  float* out = (float*)d_out;

  char* ws = (char*)d_ws;
  char* xq = ws;                                             // 32 MB i8
  char* qb = ws + (size_t)32 * 1024 * 1024;                  // 16 MB i8
  float* rx = (float*)(ws + (size_t)48 * 1024 * 1024);       // 32 KB
  float* sxf = (float*)(ws + (size_t)48 * 1024 * 1024 + 65536);  // 32 KB

  hipLaunchKernelGGL(prep_x_i8, dim3(M_DIM), dim3(256), 0, stream, x, xq, rx, sxf);
  hipLaunchKernelGGL(prep_q_i8, dim3((N_DIM * K_DIM / 4) / 256), dim3(256), 0, stream,
                     qw, qb);
  hipLaunchKernelGGL(wq_gemm_i8, dim3((M_DIM / BM) * (N_DIM / BN)), dim3(512), 0,
                     stream, xq, qb, rx, sxf, scales, zps, bias, out);
}